// Round 14
// baseline (818.073 us; speedup 1.0000x reference)
//
// build-id: r14-fused-tail (r9 main phase + per-image tail fused via done-counters)
#include <hip/hip_runtime.h>
#include <cstdint>
#include <cstddef>

#define B_      64
#define P_      24564
#define C_      81
#define NOBJ_   16
#define CHUNKS_ 96       // 256-prior chunks per image (last chunk: 244 valid)
#define NBLK_   6144     // B_*CHUNKS_
#define TILE_F  1296     // 16 rows * 81 floats
#define TILE_F4 324      // float4s per tile
#define NF4_    6141     // P_/4 (exact)

typedef unsigned long long u64;

__device__ __forceinline__ float smooth_l1(float d){
  float ad = fabsf(d);
  return (ad < 1.0f) ? 0.5f * d * d : ad - 0.5f;
}

__device__ __forceinline__ float iou_pb(float bx0, float by0, float bx1, float by1,
                                        float ba, float px0, float py0,
                                        float px1, float py1, float pa){
  float ix = fminf(bx1, px1) - fmaxf(bx0, px0);
  float iy = fminf(by1, py1) - fmaxf(by0, py0);
  ix = fmaxf(ix, 0.f); iy = fmaxf(iy, 0.f);
  float inter = ix * iy;
  return __fdividef(inter, ba + pa - inter);
}

__device__ __forceinline__ float sl1_row4(const float* sbox, int am, float4 pr, float4 pl){
  float x0 = sbox[am*4+0], y0 = sbox[am*4+1], x1 = sbox[am*4+2], y1 = sbox[am*4+3];
  float cx = (x0 + x1) / 2.f, cy = (y0 + y1) / 2.f;
  float w_ = x1 - x0, h_ = y1 - y0;
  float g0 = (cx - pr.x) / (pr.z / 10.0f);
  float g1 = (cy - pr.y) / (pr.w / 10.0f);
  float g2 = logf(w_ / pr.z) * 5.0f;
  float g3 = logf(h_ / pr.w) * 5.0f;
  return smooth_l1(pl.x - g0) + smooth_l1(pl.y - g1)
       + smooth_l1(pl.z - g2) + smooth_l1(pl.w - g3);
}

// zero the done counters (ws is poisoned 0xAA; must re-init every launch)
__global__ void k_init(int* __restrict__ done_img, int* __restrict__ done_final){
  int i = threadIdx.x;
  if (i < B_) done_img[i] = 0;
  if (i == 0) *done_final = 0;
}

// ---------------- k_main: IoU + CE per chunk; fused per-image tail ----------
__global__ __launch_bounds__(64) void k_main(const float* __restrict__ scores,
                                             const float* __restrict__ priors,
                                             const float* __restrict__ boxes,
                                             const int*   __restrict__ labels,
                                             const float* __restrict__ pred_locs,
                                             float* __restrict__ ce_neg,
                                             u64*   __restrict__ pob,
                                             int*   __restrict__ npos_c,
                                             float* __restrict__ sl1_c,
                                             float* __restrict__ cpos_c,
                                             int*   __restrict__ npos_img,
                                             float* __restrict__ sl1_img,
                                             float* __restrict__ cpos_img,
                                             float* __restrict__ hard_img,
                                             int*   __restrict__ done_img,
                                             int*   __restrict__ done_final,
                                             float* __restrict__ out){
  // LDS union: main phase {sM|lmx|lam|sbox|slab}; tail reuses sM->hist, lmx->ssel, lam->sppo
  __shared__ __align__(16) char smem[12736];
  float* sM   = (float*)smem;               // 10368 B (2 x TILE_F)
  float* lmx  = (float*)(smem + 10368);     // 1024 B
  int*   lam  = (int*)  (smem + 11392);     // 1024 B
  float* sbox = (float*)(smem + 12416);     // 256 B (live through tail)
  int*   slab = (int*)  (smem + 12672);     // 64 B  (live through tail)

  const int lane = threadIdx.x;
  const int chk = blockIdx.x, img = blockIdx.y;
  const int blkid = img * CHUNKS_ + chk;

  const int pr0  = chk * 256;
  const int nval = min(256, P_ - pr0);
  sbox[lane] = boxes[img * NOBJ_ * 4 + lane];
  if (lane < NOBJ_) slab[lane] = labels[img * NOBJ_ + lane];

  const size_t brow = (size_t)img * P_ + pr0;
  const float4* g4 = reinterpret_cast<const float4*>(scores + brow * (size_t)C_);
  const int lim = (int)(((size_t)B_ * P_ - brow) * C_ / 4) - 1;

  auto STAGE = [&](int t, float* dst){
    const int b4 = t * TILE_F4;
    #pragma unroll
    for (int k = 0; k < 5; ++k){
      int idx = min(b4 + k * 64 + lane, lim);
      __builtin_amdgcn_global_load_lds(
          (const __attribute__((address_space(1))) void*)(g4 + idx),
          (__attribute__((address_space(3))) void*)(dst + k * 256), 16, 0, 0);
    }
    int idx = min(b4 + 320 + lane, lim);
    if (lane < 4)
      __builtin_amdgcn_global_load_lds(
          (const __attribute__((address_space(1))) void*)(g4 + idx),
          (__attribute__((address_space(3))) void*)(dst + 1280), 16, 0, 0);
  };

  STAGE(0, sM);   // tile 0 flies under the IoU phase

  // ---- IoU: lane owns priors pr0 + j*64 + lane ----
  float4 prv[4]; bool pvd[4];
  #pragma unroll
  for (int j = 0; j < 4; ++j){
    int idx = j * 64 + lane;
    pvd[j] = idx < nval;
    prv[j] = reinterpret_cast<const float4*>(priors)[pr0 + (pvd[j] ? idx : 0)];
  }
  float px0[4], py0[4], px1[4], py1[4], pa[4];
  #pragma unroll
  for (int j = 0; j < 4; ++j){
    px0[j] = prv[j].x - prv[j].z * 0.5f;  py0[j] = prv[j].y - prv[j].w * 0.5f;
    px1[j] = prv[j].x + prv[j].z * 0.5f;  py1[j] = prv[j].y + prv[j].w * 0.5f;
    pa[j]  = (px1[j] - px0[j]) * (py1[j] - py0[j]);
  }
  float mx[4]; int am[4];
  #pragma unroll
  for (int j = 0; j < 4; ++j){ mx[j] = -1.f; am[j] = 0; }

  #pragma unroll
  for (int o = 0; o < NOBJ_; ++o){
    float bx0 = sbox[o*4+0], by0 = sbox[o*4+1], bx1 = sbox[o*4+2], by1 = sbox[o*4+3];
    float ba = (bx1 - bx0) * (by1 - by0);
    float bbv = -1.f; int bbi = 0x7FFFFFFF;
    #pragma unroll
    for (int j = 0; j < 4; ++j){
      float v = iou_pb(bx0, by0, bx1, by1, ba, px0[j], py0[j], px1[j], py1[j], pa[j]);
      if (!pvd[j]) v = -2.f;
      int p = pr0 + j * 64 + lane;
      if (v > bbv){ bbv = v; bbi = p; }          // j asc => first-wins
      if (v > mx[j]){ mx[j] = v; am[j] = o; }    // o asc => first-wins
    }
    #pragma unroll
    for (int off = 32; off; off >>= 1){
      float v2 = __shfl_down(bbv, off);
      int   i2 = __shfl_down(bbi, off);
      if (v2 > bbv || (v2 == bbv && i2 < bbi)){ bbv = v2; bbi = i2; }
    }
    if (lane == 0)
      pob[(size_t)blkid * NOBJ_ + o] =
          ((u64)__float_as_uint(bbv) << 32) | (u64)(0xFFFFFFFFu - (unsigned)bbi);
  }
  #pragma unroll
  for (int j = 0; j < 4; ++j){ lmx[j*64 + lane] = mx[j]; lam[j*64 + lane] = am[j]; }

  // ---- CE: 16 tiles x 16 rows, 4 lanes per row (r9-proven pipeline) ----
  int cnt = 0; float sl1 = 0.f, cpos = 0.f;
  const int rr = lane & 15, h = lane >> 4;
  const int rbase = rr * 81 + (h == 0 ? 0 : 1 + 20 * h);

  auto COMPUTE = [&](int t){
    const float* lb = sM + (t & 1) * TILE_F;
    float sa = 0.f, sb = 0.f;
    #pragma unroll
    for (int j = 0; j < 10; ++j){
      sa += __expf(lb[rbase + 2*j]);
      sb += __expf(lb[rbase + 2*j + 1]);
    }
    if (h == 0) sa += __expf(lb[rbase + 20]);
    float sum = sa + sb;
    sum += __shfl_xor(sum, 16);
    sum += __shfl_xor(sum, 32);
    if (h == 0){
      int pl_ = t * 16 + rr;
      if (pl_ < nval){
        size_t row = brow + pl_;
        float lse = __logf(sum);
        float s0  = lb[rr * 81];
        bool pos = lmx[pl_] >= 0.5f;
        ce_neg[row] = pos ? 0.f : fmaxf(lse - s0, 0.f);
        if (pos){
          int a = lam[pl_];
          int cls = slab[a];
          cpos += lse - lb[rr * 81 + cls];
          ++cnt;
          float4 pr  = reinterpret_cast<const float4*>(priors)[pr0 + pl_];
          float4 pl4 = reinterpret_cast<const float4*>(pred_locs)[row];
          sl1 += sl1_row4(sbox, a, pr, pl4);
        }
      }
    }
  };

  for (int t = 0; t < 15; ++t){
    STAGE(t + 1, sM + ((t + 1) & 1) * TILE_F);
    asm volatile("s_waitcnt vmcnt(6)" ::: "memory");
    COMPUTE(t);
  }
  asm volatile("s_waitcnt vmcnt(0)" ::: "memory");
  COMPUTE(15);

  #pragma unroll
  for (int off = 8; off; off >>= 1){
    cnt  += __shfl_down(cnt, off);
    sl1  += __shfl_down(sl1, off);
    cpos += __shfl_down(cpos, off);
  }
  if (lane == 0){
    npos_c[blkid] = cnt; sl1_c[blkid] = sl1; cpos_c[blkid] = cpos;
  }

  // ---- release chunk outputs; last chunk of the image runs the tail ----
  __threadfence();
  int old_ = 0;
  if (lane == 0) old_ = atomicAdd(&done_img[img], 1);
  old_ = __shfl(old_, 0);
  if (old_ != CHUNKS_ - 1) return;
  __threadfence();   // acquire: all 96 chunks' writes now visible

  // ================= per-image tail (single wave) =================
  int* histL = (int*)smem;               // 8 copies x 257 ints = 8224 B (over sM)
  int* ssel  = (int*)(smem + 10368);     // 2 ints (over lmx)
  int* sppo  = (int*)(smem + 11392);     // 16 ints (over lam)

  { // pob reduce over 96 chunks: o = lane&15, g = lane>>4 handles 24 chunks
    const int o = lane & 15, g = lane >> 4;
    u64 m = 0ull;
    for (int c = g * 24; c < g * 24 + 24; ++c){
      u64 e = pob[(size_t)(img * CHUNKS_ + c) * NOBJ_ + o];
      if (e > m) m = e;
    }
    u64 t1 = __shfl_down(m, 32); if (t1 > m) m = t1;
    u64 t2 = __shfl_down(m, 16); if (t2 > m) m = t2;
    if (lane < 16) sppo[lane] = (int)(0xFFFFFFFFu - (unsigned)(m & 0xFFFFFFFFull));
  }

  // chunk-partial sums
  int np_ = 0; float sl_ = 0.f, cp_ = 0.f;
  for (int c = lane; c < CHUNKS_; c += 64){
    np_ += npos_c[img * CHUNKS_ + c];
    sl_ += sl1_c[img * CHUNKS_ + c];
    cp_ += cpos_c[img * CHUNKS_ + c];
  }
  #pragma unroll
  for (int off = 32; off; off >>= 1){
    np_ += __shfl_down(np_, off);
    sl_ += __shfl_down(sl_, off);
    cp_ += __shfl_down(cp_, off);
  }

  // corrections: lanes 0..15 handle the <=16 forced priors
  int npd = 0; float sld = 0.f, cpd = 0.f;
  if (lane < 16){
    int o = lane, p = sppo[o];
    bool is_last = true;
    for (int o2 = o + 1; o2 < 16; ++o2) if (sppo[o2] == p) is_last = false;
    if (is_last){
      float4 pr = reinterpret_cast<const float4*>(priors)[p];
      float qx0 = pr.x - pr.z * 0.5f, qy0 = pr.y - pr.w * 0.5f;
      float qx1 = pr.x + pr.z * 0.5f, qy1 = pr.y + pr.w * 0.5f;
      float qa  = (qx1 - qx0) * (qy1 - qy0);
      float mxo = -1.f; int amo = 0;
      for (int oo = 0; oo < 16; ++oo){
        float bx0 = sbox[oo*4+0], by0 = sbox[oo*4+1],
              bx1 = sbox[oo*4+2], by1 = sbox[oo*4+3];
        float ba = (bx1 - bx0) * (by1 - by0);
        float v = iou_pb(bx0, by0, bx1, by1, ba, qx0, qy0, qx1, qy1, qa);
        if (v > mxo){ mxo = v; amo = oo; }
      }
      bool pos_old = mxo >= 0.5f;
      size_t row = (size_t)img * P_ + p;
      float4 pl4 = reinterpret_cast<const float4*>(pred_locs)[row];
      float sl_new = sl1_row4(sbox, o, pr, pl4);
      float s_new = scores[row * (size_t)C_ + slab[o]];
      if (pos_old){
        float sl_old = sl1_row4(sbox, amo, pr, pl4);
        float s_old  = scores[row * (size_t)C_ + slab[amo]];
        sld = sl_new - sl_old;
        cpd = s_old - s_new;               // lse cancels
      } else {
        npd = 1;
        float ce0v = ce_neg[row];          // = lse - s0 (>=0 up to rounding)
        float s0   = scores[row * (size_t)C_];
        sld = sl_new;
        cpd = ce0v + s0 - s_new;
        ce_neg[row] = 0.f;                 // now positive: excluded from topk
      }
    }
  }
  #pragma unroll
  for (int off = 8; off; off >>= 1){
    npd += __shfl_down(npd, off);
    sld += __shfl_down(sld, off);
    cpd += __shfl_down(cpd, off);
  }
  int npos_tot = 0;
  if (lane == 0){
    npos_tot = np_ + npd;
    npos_img[img] = npos_tot;
    sl1_img[img]  = sl_ + sld;
    cpos_img[img] = cp_ + cpd;
  }
  const int K = 3 * __shfl(npos_tot, 0);
  __threadfence();   // drain ce_neg[row]=0 stores before radix re-reads

  // ---- per-image exact top-K sum (float4 radix over f32 bits) ----
  const float4* v4 = reinterpret_cast<const float4*>(ce_neg + (size_t)img * P_);
  float hardv = 0.f;
  if (K >= P_){
    float s = 0.f;
    for (int i = lane; i < NF4_; i += 64){
      float4 q = v4[i]; s += q.x + q.y + q.z + q.w;
    }
    #pragma unroll
    for (int off = 32; off; off >>= 1) s += __shfl_down(s, off);
    hardv = s;
  } else if (K > 0){
    unsigned prefix = 0; int remaining = K;
    const int cpy = (lane & 7) * 257;
    for (int shift = 24; shift >= 0; shift -= 8){
      for (int i = lane; i < 8 * 257; i += 64) histL[i] = 0;
      unsigned hmask = (shift == 24) ? 0u : (0xFFFFFFFFu << (shift + 8));
      for (int i = lane; i < NF4_; i += 64){
        float4 q = v4[i];
        unsigned u;
        u = __float_as_uint(q.x); if ((u & hmask) == prefix) atomicAdd(&histL[cpy + ((u >> shift) & 255)], 1);
        u = __float_as_uint(q.y); if ((u & hmask) == prefix) atomicAdd(&histL[cpy + ((u >> shift) & 255)], 1);
        u = __float_as_uint(q.z); if ((u & hmask) == prefix) atomicAdd(&histL[cpy + ((u >> shift) & 255)], 1);
        u = __float_as_uint(q.w); if ((u & hmask) == prefix) atomicAdd(&histL[cpy + ((u >> shift) & 255)], 1);
      }
      int a0 = 0, a1 = 0, a2 = 0, a3 = 0;
      #pragma unroll
      for (int w = 0; w < 8; ++w){
        a0 += histL[w * 257 + lane * 4 + 0];
        a1 += histL[w * 257 + lane * 4 + 1];
        a2 += histL[w * 257 + lane * 4 + 2];
        a3 += histL[w * 257 + lane * 4 + 3];
      }
      int tl = a0 + a1 + a2 + a3, run = tl;
      #pragma unroll
      for (int off = 1; off < 64; off <<= 1){
        int x = __shfl_down(run, off);
        if (lane + off < 64) run += x;
      }
      int E  = run - tl;   // elements in bins above this lane's 4 bins
      int s3 = E, s2 = s3 + a3, s1 = s2 + a2, s0 = s1 + a1;
      if (s0 < remaining && s0 + a0 >= remaining){ ssel[0] = (int)(prefix | ((unsigned)(lane*4+0) << shift)); ssel[1] = remaining - s0; }
      if (s1 < remaining && s1 + a1 >= remaining){ ssel[0] = (int)(prefix | ((unsigned)(lane*4+1) << shift)); ssel[1] = remaining - s1; }
      if (s2 < remaining && s2 + a2 >= remaining){ ssel[0] = (int)(prefix | ((unsigned)(lane*4+2) << shift)); ssel[1] = remaining - s2; }
      if (s3 < remaining && s3 + a3 >= remaining){ ssel[0] = (int)(prefix | ((unsigned)(lane*4+3) << shift)); ssel[1] = remaining - s3; }
      prefix = (unsigned)ssel[0];
      remaining = ssel[1];
    }
    float tv = __uint_as_float(prefix);
    float sgt = 0.f;
    for (int i = lane; i < NF4_; i += 64){
      float4 q = v4[i];
      if (__float_as_uint(q.x) > prefix) sgt += q.x;
      if (__float_as_uint(q.y) > prefix) sgt += q.y;
      if (__float_as_uint(q.z) > prefix) sgt += q.z;
      if (__float_as_uint(q.w) > prefix) sgt += q.w;
    }
    #pragma unroll
    for (int off = 32; off; off >>= 1) sgt += __shfl_down(sgt, off);
    hardv = sgt + (float)remaining * tv;
  }

  // ---- final combine (last image to finish) ----
  int last = 0;
  if (lane == 0){
    hard_img[img] = hardv;
    __threadfence();
    last = (atomicAdd(done_final, 1) == B_ - 1) ? 1 : 0;
  }
  last = __shfl(last, 0);
  if (!last) return;
  __threadfence();   // acquire
  float np = (float)npos_img[lane];
  float sl = sl1_img[lane];
  float cp = cpos_img[lane];
  float hd = hard_img[lane];
  #pragma unroll
  for (int off = 32; off; off >>= 1){
    np += __shfl_down(np, off);
    sl += __shfl_down(sl, off);
    cp += __shfl_down(cp, off);
    hd += __shfl_down(hd, off);
  }
  if (lane == 0)
    out[0] = (hd + cp) / np + sl / (np * 4.0f);
}

extern "C" void kernel_launch(void* const* d_in, const int* in_sizes, int n_in,
                              void* d_out, int out_size, void* d_ws, size_t ws_size,
                              hipStream_t stream){
  const float* pred_locs = (const float*)d_in[0];
  const float* scores    = (const float*)d_in[1];
  const float* boxes     = (const float*)d_in[2];
  const int*   labels    = (const int*)d_in[3];
  const float* priors    = (const float*)d_in[4];

  const size_t BP = (size_t)B_ * P_;
  char* w = (char*)d_ws;
  float* ce_neg = (float*)w;                                   // BP f32
  u64*   pob    = (u64*)(w + BP * 4);                          // NBLK_*16 u64
  char*  w2 = w + BP * 4 + (size_t)NBLK_ * NOBJ_ * 8;
  int*   npos_c = (int*)  w2;                                  // NBLK_
  float* sl1_c  = (float*)(w2 + NBLK_ * 4);                    // NBLK_
  float* cpos_c = (float*)(w2 + NBLK_ * 8);                    // NBLK_
  char*  w3 = w2 + NBLK_ * 12;
  int*   npos_img   = (int*)  w3;                              // 64
  float* sl1_img    = (float*)(w3 + 256);
  float* cpos_img   = (float*)(w3 + 512);
  float* hard_img   = (float*)(w3 + 768);
  int*   done_img   = (int*)  (w3 + 1024);                     // 64
  int*   done_final = (int*)  (w3 + 1280);                     // 1

  k_init<<<1, 128, 0, stream>>>(done_img, done_final);

  dim3 g1(CHUNKS_, B_);
  k_main<<<g1, 64, 0, stream>>>(scores, priors, boxes, labels, pred_locs,
                                ce_neg, pob, npos_c, sl1_c, cpos_c,
                                npos_img, sl1_img, cpos_img, hard_img,
                                done_img, done_final, (float*)d_out);
}

// Round 15
// 197.942 us; speedup vs baseline: 4.1329x; 4.1329x over previous
//
// build-id: r15-8row-tiles (r9 two-kernel structure; LDS 7.6KB -> 21 blocks/CU)
#include <hip/hip_runtime.h>
#include <cstdint>
#include <cstddef>

#define B_      64
#define P_      24564
#define C_      81
#define NOBJ_   16
#define CHUNKS_ 96       // 256-prior chunks per image (last chunk: 244 valid)
#define NBLK_   6144     // B_*CHUNKS_
#define TILE_F  648      // 8 rows * 81 floats
#define TILE_F4 162      // float4s per tile (2 full-wave gload_lds + 34 lanes)

typedef unsigned long long u64;

__device__ __forceinline__ float smooth_l1(float d){
  float ad = fabsf(d);
  return (ad < 1.0f) ? 0.5f * d * d : ad - 0.5f;
}

__device__ __forceinline__ float iou_pb(float bx0, float by0, float bx1, float by1,
                                        float ba, float px0, float py0,
                                        float px1, float py1, float pa){
  float ix = fminf(bx1, px1) - fmaxf(bx0, px0);
  float iy = fminf(by1, py1) - fmaxf(by0, py0);
  ix = fmaxf(ix, 0.f); iy = fmaxf(iy, 0.f);
  float inter = ix * iy;
  return __fdividef(inter, ba + pa - inter);
}

__device__ __forceinline__ float sl1_row4(const float* sbox, int am, float4 pr, float4 pl){
  float x0 = sbox[am*4+0], y0 = sbox[am*4+1], x1 = sbox[am*4+2], y1 = sbox[am*4+3];
  float cx = (x0 + x1) / 2.f, cy = (y0 + y1) / 2.f;
  float w_ = x1 - x0, h_ = y1 - y0;
  float g0 = (cx - pr.x) / (pr.z / 10.0f);
  float g1 = (cy - pr.y) / (pr.w / 10.0f);
  float g2 = logf(w_ / pr.z) * 5.0f;
  float g3 = logf(h_ / pr.w) * 5.0f;
  return smooth_l1(pl.x - g0) + smooth_l1(pl.y - g1)
       + smooth_l1(pl.z - g2) + smooth_l1(pl.w - g3);
}

// ---------------- k_main: per-chunk IoU + CE over the SAME 256 rows ----------
// grid (96, 64) x 64 threads. CE: 32 tiles x 8 rows, 8 lanes/row, double-
// buffered global_load_lds (3 ops/tile) with counted s_waitcnt vmcnt(3).
__global__ __launch_bounds__(64) void k_main(const float* __restrict__ scores,
                                             const float* __restrict__ priors,
                                             const float* __restrict__ boxes,
                                             const int*   __restrict__ labels,
                                             const float* __restrict__ pred_locs,
                                             float* __restrict__ ce_neg,
                                             u64*   __restrict__ pob,
                                             int*   __restrict__ npos_c,
                                             float* __restrict__ sl1_c,
                                             float* __restrict__ cpos_c,
                                             int*   __restrict__ done){
  __shared__ float sM[2 * TILE_F];    // 5184 B
  __shared__ float lmx[256];
  __shared__ int   lam[256];
  __shared__ float sbox[NOBJ_ * 4];
  __shared__ int   slab[NOBJ_];
  const int lane = threadIdx.x;
  const int chk = blockIdx.x, img = blockIdx.y;
  const int blkid = img * CHUNKS_ + chk;
  if (blkid == 0 && lane == 0) *done = 0;   // stream-ordered reset for k_tail

  const int pr0  = chk * 256;
  const int nval = min(256, P_ - pr0);
  sbox[lane] = boxes[img * NOBJ_ * 4 + lane];
  if (lane < NOBJ_) slab[lane] = labels[img * NOBJ_ + lane];

  const size_t brow = (size_t)img * P_ + pr0;
  const float4* g4 = reinterpret_cast<const float4*>(scores + brow * (size_t)C_);
  const int lim = (int)(((size_t)B_ * P_ - brow) * C_ / 4) - 1;

  auto STAGE = [&](int t, float* dst){
    const int b4 = t * TILE_F4;
    #pragma unroll
    for (int k = 0; k < 2; ++k){
      int idx = min(b4 + k * 64 + lane, lim);
      __builtin_amdgcn_global_load_lds(
          (const __attribute__((address_space(1))) void*)(g4 + idx),
          (__attribute__((address_space(3))) void*)(dst + k * 256), 16, 0, 0);
    }
    int idx = min(b4 + 128 + lane, lim);
    if (lane < 34)
      __builtin_amdgcn_global_load_lds(
          (const __attribute__((address_space(1))) void*)(g4 + idx),
          (__attribute__((address_space(3))) void*)(dst + 512), 16, 0, 0);
  };

  STAGE(0, sM);   // tile 0 flies under the IoU phase

  // ---- IoU: lane owns priors pr0 + j*64 + lane ----
  float4 prv[4]; bool pvd[4];
  #pragma unroll
  for (int j = 0; j < 4; ++j){
    int idx = j * 64 + lane;
    pvd[j] = idx < nval;
    prv[j] = reinterpret_cast<const float4*>(priors)[pr0 + (pvd[j] ? idx : 0)];
  }
  float px0[4], py0[4], px1[4], py1[4], pa[4];
  #pragma unroll
  for (int j = 0; j < 4; ++j){
    px0[j] = prv[j].x - prv[j].z * 0.5f;  py0[j] = prv[j].y - prv[j].w * 0.5f;
    px1[j] = prv[j].x + prv[j].z * 0.5f;  py1[j] = prv[j].y + prv[j].w * 0.5f;
    pa[j]  = (px1[j] - px0[j]) * (py1[j] - py0[j]);
  }
  float mx[4]; int am[4];
  #pragma unroll
  for (int j = 0; j < 4; ++j){ mx[j] = -1.f; am[j] = 0; }

  #pragma unroll
  for (int o = 0; o < NOBJ_; ++o){
    float bx0 = sbox[o*4+0], by0 = sbox[o*4+1], bx1 = sbox[o*4+2], by1 = sbox[o*4+3];
    float ba = (bx1 - bx0) * (by1 - by0);
    float bbv = -1.f; int bbi = 0x7FFFFFFF;
    #pragma unroll
    for (int j = 0; j < 4; ++j){
      float v = iou_pb(bx0, by0, bx1, by1, ba, px0[j], py0[j], px1[j], py1[j], pa[j]);
      if (!pvd[j]) v = -2.f;
      int p = pr0 + j * 64 + lane;
      if (v > bbv){ bbv = v; bbi = p; }          // j asc => first-wins
      if (v > mx[j]){ mx[j] = v; am[j] = o; }    // o asc => first-wins
    }
    #pragma unroll
    for (int off = 32; off; off >>= 1){
      float v2 = __shfl_down(bbv, off);
      int   i2 = __shfl_down(bbi, off);
      if (v2 > bbv || (v2 == bbv && i2 < bbi)){ bbv = v2; bbi = i2; }
    }
    if (lane == 0)
      pob[(size_t)blkid * NOBJ_ + o] =
          ((u64)__float_as_uint(bbv) << 32) | (u64)(0xFFFFFFFFu - (unsigned)bbi);
  }
  #pragma unroll
  for (int j = 0; j < 4; ++j){ lmx[j*64 + lane] = mx[j]; lam[j*64 + lane] = am[j]; }

  // ---- CE: 32 tiles x 8 rows, 8 lanes per row ----
  int cnt = 0; float sl1 = 0.f, cpos = 0.f;
  const int r = lane >> 3, sub = lane & 7;
  const int rbase = r * 81 + (sub == 0 ? 0 : 11 + (sub - 1) * 10);  // 11/10..10 cols

  auto COMPUTE = [&](int t){
    const float* lb = sM + (t & 1) * TILE_F;
    float sa = 0.f, sb = 0.f;
    #pragma unroll
    for (int j = 0; j < 5; ++j){
      sa += __expf(lb[rbase + 2*j]);
      sb += __expf(lb[rbase + 2*j + 1]);
    }
    if (sub == 0) sa += __expf(lb[rbase + 10]);
    float sum = sa + sb;
    sum += __shfl_xor(sum, 1);
    sum += __shfl_xor(sum, 2);
    sum += __shfl_xor(sum, 4);
    if (sub == 0){
      int pl_ = t * 8 + r;
      if (pl_ < nval){
        size_t row = brow + pl_;
        float lse = __logf(sum);
        float s0  = lb[r * 81];
        bool pos = lmx[pl_] >= 0.5f;
        ce_neg[row] = pos ? 0.f : fmaxf(lse - s0, 0.f);
        if (pos){
          int a = lam[pl_];
          int cls = slab[a];
          cpos += lse - lb[r * 81 + cls];
          ++cnt;
          float4 pr  = reinterpret_cast<const float4*>(priors)[pr0 + pl_];
          float4 pl4 = reinterpret_cast<const float4*>(pred_locs)[row];
          sl1 += sl1_row4(sbox, a, pr, pl4);
        }
      }
    }
  };

  for (int t = 0; t < 31; ++t){
    STAGE(t + 1, sM + ((t + 1) & 1) * TILE_F);
    asm volatile("s_waitcnt vmcnt(3)" ::: "memory");   // tile t ready; t+1 flying
    COMPUTE(t);
  }
  asm volatile("s_waitcnt vmcnt(0)" ::: "memory");
  COMPUTE(31);

  #pragma unroll
  for (int off = 32; off; off >>= 1){
    cnt  += __shfl_down(cnt, off);
    sl1  += __shfl_down(sl1, off);
    cpos += __shfl_down(cpos, off);
  }
  if (lane == 0){
    npos_c[blkid] = cnt; sl1_c[blkid] = sl1; cpos_c[blkid] = cpos;
  }
}

// ---------------- k_tail: forced-match corrections + top-K + final ----------
// grid 64 x 1024. One block per image. (verbatim r12, passing)
__global__ __launch_bounds__(1024) void k_tail(const float* __restrict__ scores,
                                               const float* __restrict__ priors,
                                               const float* __restrict__ boxes,
                                               const int*   __restrict__ labels,
                                               const float* __restrict__ pred_locs,
                                               const u64*   __restrict__ pob,
                                               const int*   __restrict__ npos_c,
                                               const float* __restrict__ sl1_c,
                                               const float* __restrict__ cpos_c,
                                               float* __restrict__ ce_neg,
                                               int*   __restrict__ npos_img,
                                               float* __restrict__ sl1_img,
                                               float* __restrict__ cpos_img,
                                               float* __restrict__ hard_img,
                                               int*   __restrict__ done,
                                               float* __restrict__ out){
  const int img = blockIdx.x, tid = threadIdx.x;
  const int lane = tid & 63, wid = tid >> 6;
  __shared__ u64   pm[64][NOBJ_];
  __shared__ int   sppo[NOBJ_];
  __shared__ float sbox[NOBJ_ * 4];
  __shared__ int   slab[NOBJ_];
  __shared__ float sredA[96], sredB[96];
  __shared__ int   sredI[96];
  __shared__ int   s_npos;
  __shared__ float s_sl1, s_cpos, s_hard;
  __shared__ int   s_last;

  if (tid < 64) sbox[tid] = boxes[img * 64 + tid];
  if (tid < 16) slab[tid] = labels[img * 16 + tid];
  {
    int o = tid & 15, g = tid >> 4;    // g in [0,64)
    u64 m = pob[(size_t)(img * CHUNKS_ + g) * NOBJ_ + o];
    if (g < 32){
      u64 e = pob[(size_t)(img * CHUNKS_ + 64 + g) * NOBJ_ + o];
      if (e > m) m = e;
    }
    pm[g][o] = m;
  }
  if (tid < 96){
    sredI[tid] = npos_c[img * CHUNKS_ + tid];
    sredA[tid] = sl1_c[img * CHUNKS_ + tid];
    sredB[tid] = cpos_c[img * CHUNKS_ + tid];
  }
  __syncthreads();
  if (tid < 16){
    u64 m = pm[0][tid];
    for (int g = 1; g < 64; ++g) if (pm[g][tid] > m) m = pm[g][tid];
    sppo[tid] = (int)(0xFFFFFFFFu - (unsigned)(m & 0xFFFFFFFFull));
  }
  if (tid == 0){
    int c = 0; float s = 0.f, q = 0.f;
    for (int i = 0; i < 96; ++i){ c += sredI[i]; s += sredA[i]; q += sredB[i]; }
    s_npos = c; s_sl1 = s; s_cpos = q;
  }
  __syncthreads();

  // corrections: lanes 0..15 of wave 0 handle the <=16 forced priors
  int npd = 0; float sld = 0.f, cpd = 0.f;
  if (wid == 0 && lane < 16){
    int o = lane, p = sppo[o];
    bool is_last = true;
    for (int o2 = o + 1; o2 < 16; ++o2) if (sppo[o2] == p) is_last = false;
    if (is_last){
      float4 pr = reinterpret_cast<const float4*>(priors)[p];
      float px0 = pr.x - pr.z * 0.5f, py0 = pr.y - pr.w * 0.5f;
      float px1 = pr.x + pr.z * 0.5f, py1 = pr.y + pr.w * 0.5f;
      float pa  = (px1 - px0) * (py1 - py0);
      float mxo = -1.f; int amo = 0;
      for (int oo = 0; oo < 16; ++oo){
        float bx0 = sbox[oo*4+0], by0 = sbox[oo*4+1],
              bx1 = sbox[oo*4+2], by1 = sbox[oo*4+3];
        float ba = (bx1 - bx0) * (by1 - by0);
        float v = iou_pb(bx0, by0, bx1, by1, ba, px0, py0, px1, py1, pa);
        if (v > mxo){ mxo = v; amo = oo; }
      }
      bool pos_old = mxo >= 0.5f;
      size_t row = (size_t)img * P_ + p;
      float4 pl4 = reinterpret_cast<const float4*>(pred_locs)[row];
      float sl_new = sl1_row4(sbox, o, pr, pl4);
      int lab_new = slab[o];
      float s_new = scores[row * (size_t)C_ + lab_new];
      if (pos_old){
        float sl_old = sl1_row4(sbox, amo, pr, pl4);
        float s_old  = scores[row * (size_t)C_ + slab[amo]];
        sld = sl_new - sl_old;
        cpd = s_old - s_new;               // lse cancels
      } else {
        npd = 1;
        float ce0v = ce_neg[row];          // = lse - s0 (>=0 up to rounding)
        float s0   = scores[row * (size_t)C_];
        sld = sl_new;
        cpd = ce0v + s0 - s_new;
        ce_neg[row] = 0.f;                 // now positive: excluded from topk
      }
    }
  }
  if (wid == 0){
    #pragma unroll
    for (int off = 8; off; off >>= 1){
      npd += __shfl_down(npd, off);
      sld += __shfl_down(sld, off);
      cpd += __shfl_down(cpd, off);
    }
    if (lane == 0){
      s_npos += npd; s_sl1 += sld; s_cpos += cpd;
      npos_img[img] = s_npos; sl1_img[img] = s_sl1; cpos_img[img] = s_cpos;
    }
  }
  __threadfence();
  __syncthreads();

  // ---- per-image exact top-K sum (radix select over f32 bits) ----
  const int K = 3 * s_npos;
  const float* v = ce_neg + (size_t)img * P_;
  __shared__ int hist[32 * 257];
  __shared__ int histT[256];
  __shared__ unsigned s_prefix;
  __shared__ int s_rem;
  __shared__ float rsum[16];
  const int copy = tid & 31;

  if (K <= 0){
    if (tid == 0) s_hard = 0.f;
    __syncthreads();
  } else if (K >= P_){
    float s = 0.f;
    for (int p = tid; p < P_; p += 1024) s += v[p];
    #pragma unroll
    for (int off = 32; off; off >>= 1) s += __shfl_down(s, off);
    if (lane == 0) rsum[wid] = s;
    __syncthreads();
    if (tid == 0){
      float t = 0.f;
      for (int w = 0; w < 16; ++w) t += rsum[w];
      s_hard = t;
    }
    __syncthreads();
  } else {
    unsigned prefix = 0; int remaining = K;
    for (int shift = 24; shift >= 0; shift -= 8){
      for (int i = tid; i < 32 * 257; i += 1024) hist[i] = 0;
      __syncthreads();
      unsigned hmask = (shift == 24) ? 0u : (0xFFFFFFFFu << (shift + 8));
      for (int p = tid; p < P_; p += 1024){
        unsigned u = __float_as_uint(v[p]);
        if ((u & hmask) == prefix) atomicAdd(&hist[copy * 257 + ((u >> shift) & 255)], 1);
      }
      __syncthreads();
      if (tid < 256){
        int s = 0;
        #pragma unroll
        for (int w = 0; w < 32; ++w) s += hist[w * 257 + tid];
        histT[tid] = s;
      }
      __syncthreads();
      if (wid == 0){
        int a0 = histT[lane*4+0], a1 = histT[lane*4+1],
            a2 = histT[lane*4+2], a3 = histT[lane*4+3];
        int tl = a0 + a1 + a2 + a3;
        int run = tl;
        #pragma unroll
        for (int off = 1; off < 64; off <<= 1){
          int x = __shfl_down(run, off);
          if (lane + off < 64) run += x;
        }
        int E  = run - tl;
        int s3 = E;
        int s2 = s3 + a3;
        int s1 = s2 + a2;
        int s0 = s1 + a1;
        if (s0 < remaining && s0 + a0 >= remaining){ s_prefix = prefix | ((unsigned)(lane*4+0) << shift); s_rem = remaining - s0; }
        if (s1 < remaining && s1 + a1 >= remaining){ s_prefix = prefix | ((unsigned)(lane*4+1) << shift); s_rem = remaining - s1; }
        if (s2 < remaining && s2 + a2 >= remaining){ s_prefix = prefix | ((unsigned)(lane*4+2) << shift); s_rem = remaining - s2; }
        if (s3 < remaining && s3 + a3 >= remaining){ s_prefix = prefix | ((unsigned)(lane*4+3) << shift); s_rem = remaining - s3; }
      }
      __syncthreads();
      prefix = s_prefix;
      remaining = s_rem;
      __syncthreads();
    }
    float tv = __uint_as_float(prefix);
    float sgt = 0.f;
    for (int p = tid; p < P_; p += 1024){
      unsigned u = __float_as_uint(v[p]);
      if (u > prefix) sgt += v[p];
    }
    #pragma unroll
    for (int off = 32; off; off >>= 1) sgt += __shfl_down(sgt, off);
    if (lane == 0) rsum[wid] = sgt;
    __syncthreads();
    if (tid == 0){
      float s = 0.f;
      for (int w = 0; w < 16; ++w) s += rsum[w];
      s_hard = s + (float)remaining * tv;
    }
    __syncthreads();
  }

  // ---- fused final combine (last block) ----
  if (tid == 0){
    hard_img[img] = s_hard;
    __threadfence();
    int old = atomicAdd(done, 1);
    s_last = (old == B_ - 1) ? 1 : 0;
  }
  __syncthreads();
  if (s_last){
    if (tid == 0) __threadfence();   // acquire: order gather loads after done RMW
    __syncthreads();
    float np = 0.f, sl = 0.f, cp = 0.f, hd = 0.f;
    if (tid < 64){
      np = (float)__hip_atomic_load(&npos_img[tid], __ATOMIC_RELAXED, __HIP_MEMORY_SCOPE_AGENT);
      sl = __hip_atomic_load(&sl1_img[tid],  __ATOMIC_RELAXED, __HIP_MEMORY_SCOPE_AGENT);
      cp = __hip_atomic_load(&cpos_img[tid], __ATOMIC_RELAXED, __HIP_MEMORY_SCOPE_AGENT);
      hd = __hip_atomic_load(&hard_img[tid], __ATOMIC_RELAXED, __HIP_MEMORY_SCOPE_AGENT);
    }
    if (wid == 0){
      #pragma unroll
      for (int off = 32; off; off >>= 1){
        np += __shfl_down(np, off);
        sl += __shfl_down(sl, off);
        cp += __shfl_down(cp, off);
        hd += __shfl_down(hd, off);
      }
      if (lane == 0){
        out[0] = (hd + cp) / np + sl / (np * 4.0f);
      }
    }
  }
}

extern "C" void kernel_launch(void* const* d_in, const int* in_sizes, int n_in,
                              void* d_out, int out_size, void* d_ws, size_t ws_size,
                              hipStream_t stream){
  const float* pred_locs = (const float*)d_in[0];
  const float* scores    = (const float*)d_in[1];
  const float* boxes     = (const float*)d_in[2];
  const int*   labels    = (const int*)d_in[3];
  const float* priors    = (const float*)d_in[4];

  const size_t BP = (size_t)B_ * P_;
  char* w = (char*)d_ws;
  float* ce_neg = (float*)w;                                   // BP f32
  u64*   pob    = (u64*)(w + BP * 4);                          // NBLK_*16 u64
  char*  w2 = w + BP * 4 + (size_t)NBLK_ * NOBJ_ * 8;
  int*   npos_c = (int*)  w2;                                  // NBLK_
  float* sl1_c  = (float*)(w2 + NBLK_ * 4);                    // NBLK_
  float* cpos_c = (float*)(w2 + NBLK_ * 8);                    // NBLK_
  char*  w3 = w2 + NBLK_ * 12;
  int*   npos_img = (int*)  w3;                                // 64
  float* sl1_img  = (float*)(w3 + 256);
  float* cpos_img = (float*)(w3 + 512);
  float* hard_img = (float*)(w3 + 768);
  int*   done     = (int*)  (w3 + 1024);

  dim3 g1(CHUNKS_, B_);
  k_main<<<g1, 64, 0, stream>>>(scores, priors, boxes, labels, pred_locs,
                                ce_neg, pob, npos_c, sl1_c, cpos_c, done);

  k_tail<<<B_, 1024, 0, stream>>>(scores, priors, boxes, labels, pred_locs,
                                  pob, npos_c, sl1_c, cpos_c, ce_neg,
                                  npos_img, sl1_img, cpos_img, hard_img,
                                  done, (float*)d_out);
}

// Round 16
// 183.366 us; speedup vs baseline: 4.4614x; 1.0795x over previous
//
// build-id: r16-restore-r9-best (16-row tiles, 2-buf vmcnt(6); best measured 182.6us)
#include <hip/hip_runtime.h>
#include <cstdint>
#include <cstddef>

#define B_      64
#define P_      24564
#define C_      81
#define NOBJ_   16
#define CHUNKS_ 96       // 256-prior chunks per image (last chunk: 244 valid)
#define NBLK_   6144     // B_*CHUNKS_
#define TILE_F  1296     // 16 rows * 81 floats
#define TILE_F4 324      // float4s per tile (5 full-wave gload_lds + 4 lanes)

typedef unsigned long long u64;

__device__ __forceinline__ float smooth_l1(float d){
  float ad = fabsf(d);
  return (ad < 1.0f) ? 0.5f * d * d : ad - 0.5f;
}

// identical arithmetic used by BOTH kernels (k_tail must reproduce k_main's
// per-prior argmax decisions)
__device__ __forceinline__ float iou_pb(float bx0, float by0, float bx1, float by1,
                                        float ba, float px0, float py0,
                                        float px1, float py1, float pa){
  float ix = fminf(bx1, px1) - fmaxf(bx0, px0);
  float iy = fminf(by1, py1) - fmaxf(by0, py0);
  ix = fmaxf(ix, 0.f); iy = fmaxf(iy, 0.f);
  float inter = ix * iy;
  return __fdividef(inter, ba + pa - inter);
}

__device__ __forceinline__ float sl1_row4(const float* sbox, int am, float4 pr, float4 pl){
  float x0 = sbox[am*4+0], y0 = sbox[am*4+1], x1 = sbox[am*4+2], y1 = sbox[am*4+3];
  float cx = (x0 + x1) / 2.f, cy = (y0 + y1) / 2.f;
  float w_ = x1 - x0, h_ = y1 - y0;
  float g0 = (cx - pr.x) / (pr.z / 10.0f);
  float g1 = (cy - pr.y) / (pr.w / 10.0f);
  float g2 = logf(w_ / pr.z) * 5.0f;
  float g3 = logf(h_ / pr.w) * 5.0f;
  return smooth_l1(pl.x - g0) + smooth_l1(pl.y - g1)
       + smooth_l1(pl.z - g2) + smooth_l1(pl.w - g3);
}

// ---------------- k_main: per-chunk IoU + CE over the SAME 256 rows ----------
// grid (96, 64) x 64 threads. Block (chk, img) owns priors/rows [pr0, pr0+256).
// CE pipeline: 16 tiles x 16 rows, double-buffered global_load_lds with
// counted s_waitcnt vmcnt(6) (tile t ready; tile t+1 in flight).
__global__ __launch_bounds__(64) void k_main(const float* __restrict__ scores,
                                             const float* __restrict__ priors,
                                             const float* __restrict__ boxes,
                                             const int*   __restrict__ labels,
                                             const float* __restrict__ pred_locs,
                                             float* __restrict__ ce_neg,
                                             u64*   __restrict__ pob,
                                             int*   __restrict__ npos_c,
                                             float* __restrict__ sl1_c,
                                             float* __restrict__ cpos_c,
                                             int*   __restrict__ done){
  __shared__ float sM[2 * TILE_F];
  __shared__ float lmx[256];
  __shared__ int   lam[256];
  __shared__ float sbox[NOBJ_ * 4];
  __shared__ int   slab[NOBJ_];
  const int lane = threadIdx.x;
  const int chk = blockIdx.x, img = blockIdx.y;
  const int blkid = img * CHUNKS_ + chk;
  if (blkid == 0 && lane == 0) *done = 0;   // stream-ordered reset for k_tail

  const int pr0  = chk * 256;
  const int nval = min(256, P_ - pr0);
  sbox[lane] = boxes[img * NOBJ_ * 4 + lane];
  if (lane < NOBJ_) slab[lane] = labels[img * NOBJ_ + lane];

  const size_t brow = (size_t)img * P_ + pr0;
  const float4* g4 = reinterpret_cast<const float4*>(scores + brow * (size_t)C_);
  // clamp index so the very last block never reads past the scores buffer
  const int lim = (int)(((size_t)B_ * P_ - brow) * C_ / 4) - 1;

  auto STAGE = [&](int t, float* dst){
    const int b4 = t * TILE_F4;
    #pragma unroll
    for (int k = 0; k < 5; ++k){
      int idx = min(b4 + k * 64 + lane, lim);
      __builtin_amdgcn_global_load_lds(
          (const __attribute__((address_space(1))) void*)(g4 + idx),
          (__attribute__((address_space(3))) void*)(dst + k * 256), 16, 0, 0);
    }
    int idx = min(b4 + 320 + lane, lim);
    if (lane < 4)
      __builtin_amdgcn_global_load_lds(
          (const __attribute__((address_space(1))) void*)(g4 + idx),
          (__attribute__((address_space(3))) void*)(dst + 1280), 16, 0, 0);
  };

  STAGE(0, sM);   // tile 0 flies under the IoU phase

  // ---- IoU: lane owns priors pr0 + j*64 + lane ----
  float4 prv[4]; bool pvd[4];
  #pragma unroll
  for (int j = 0; j < 4; ++j){
    int idx = j * 64 + lane;
    pvd[j] = idx < nval;
    prv[j] = reinterpret_cast<const float4*>(priors)[pr0 + (pvd[j] ? idx : 0)];
  }
  float px0[4], py0[4], px1[4], py1[4], pa[4];
  #pragma unroll
  for (int j = 0; j < 4; ++j){
    px0[j] = prv[j].x - prv[j].z * 0.5f;  py0[j] = prv[j].y - prv[j].w * 0.5f;
    px1[j] = prv[j].x + prv[j].z * 0.5f;  py1[j] = prv[j].y + prv[j].w * 0.5f;
    pa[j]  = (px1[j] - px0[j]) * (py1[j] - py0[j]);
  }
  float mx[4]; int am[4];
  #pragma unroll
  for (int j = 0; j < 4; ++j){ mx[j] = -1.f; am[j] = 0; }

  #pragma unroll
  for (int o = 0; o < NOBJ_; ++o){
    float bx0 = sbox[o*4+0], by0 = sbox[o*4+1], bx1 = sbox[o*4+2], by1 = sbox[o*4+3];
    float ba = (bx1 - bx0) * (by1 - by0);
    float bbv = -1.f; int bbi = 0x7FFFFFFF;
    #pragma unroll
    for (int j = 0; j < 4; ++j){
      float v = iou_pb(bx0, by0, bx1, by1, ba, px0[j], py0[j], px1[j], py1[j], pa[j]);
      if (!pvd[j]) v = -2.f;
      int p = pr0 + j * 64 + lane;
      if (v > bbv){ bbv = v; bbi = p; }          // j asc => first-wins
      if (v > mx[j]){ mx[j] = v; am[j] = o; }    // o asc => first-wins
    }
    #pragma unroll
    for (int off = 32; off; off >>= 1){
      float v2 = __shfl_down(bbv, off);
      int   i2 = __shfl_down(bbi, off);
      if (v2 > bbv || (v2 == bbv && i2 < bbi)){ bbv = v2; bbi = i2; }
    }
    if (lane == 0)
      pob[(size_t)blkid * NOBJ_ + o] =
          ((u64)__float_as_uint(bbv) << 32) | (u64)(0xFFFFFFFFu - (unsigned)bbi);
  }
  #pragma unroll
  for (int j = 0; j < 4; ++j){ lmx[j*64 + lane] = mx[j]; lam[j*64 + lane] = am[j]; }

  // ---- CE: 16 tiles x 16 rows, 4 lanes per row ----
  int cnt = 0; float sl1 = 0.f, cpos = 0.f;
  const int rr = lane & 15, h = lane >> 4;
  const int rbase = rr * 81 + (h == 0 ? 0 : 1 + 20 * h);   // h0:21, h1-3:20 elems

  auto COMPUTE = [&](int t){
    const float* lb = sM + (t & 1) * TILE_F;
    float sa = 0.f, sb = 0.f;
    #pragma unroll
    for (int j = 0; j < 10; ++j){
      sa += __expf(lb[rbase + 2*j]);
      sb += __expf(lb[rbase + 2*j + 1]);
    }
    if (h == 0) sa += __expf(lb[rbase + 20]);
    float sum = sa + sb;
    sum += __shfl_xor(sum, 16);
    sum += __shfl_xor(sum, 32);
    if (h == 0){
      int pl_ = t * 16 + rr;
      if (pl_ < nval){
        size_t row = brow + pl_;
        float lse = __logf(sum);
        float s0  = lb[rr * 81];
        bool pos = lmx[pl_] >= 0.5f;
        ce_neg[row] = pos ? 0.f : fmaxf(lse - s0, 0.f);
        if (pos){
          int a = lam[pl_];
          int cls = slab[a];
          cpos += lse - lb[rr * 81 + cls];
          ++cnt;
          float4 pr  = reinterpret_cast<const float4*>(priors)[pr0 + pl_];
          float4 pl4 = reinterpret_cast<const float4*>(pred_locs)[row];
          sl1 += sl1_row4(sbox, a, pr, pl4);
        }
      }
    }
  };

  for (int t = 0; t < 15; ++t){
    STAGE(t + 1, sM + ((t + 1) & 1) * TILE_F);
    asm volatile("s_waitcnt vmcnt(6)" ::: "memory");   // tile t ready; t+1 flying
    COMPUTE(t);
  }
  asm volatile("s_waitcnt vmcnt(0)" ::: "memory");
  COMPUTE(15);

  #pragma unroll
  for (int off = 8; off; off >>= 1){
    cnt  += __shfl_down(cnt, off);
    sl1  += __shfl_down(sl1, off);
    cpos += __shfl_down(cpos, off);
  }
  if (lane == 0){
    npos_c[blkid] = cnt; sl1_c[blkid] = sl1; cpos_c[blkid] = cpos;
  }
}

// ---------------- k_tail: forced-match corrections + top-K + final ----------
// grid 64 x 1024. One block per image.
__global__ __launch_bounds__(1024) void k_tail(const float* __restrict__ scores,
                                               const float* __restrict__ priors,
                                               const float* __restrict__ boxes,
                                               const int*   __restrict__ labels,
                                               const float* __restrict__ pred_locs,
                                               const u64*   __restrict__ pob,
                                               const int*   __restrict__ npos_c,
                                               const float* __restrict__ sl1_c,
                                               const float* __restrict__ cpos_c,
                                               float* __restrict__ ce_neg,
                                               int*   __restrict__ npos_img,
                                               float* __restrict__ sl1_img,
                                               float* __restrict__ cpos_img,
                                               float* __restrict__ hard_img,
                                               int*   __restrict__ done,
                                               float* __restrict__ out){
  const int img = blockIdx.x, tid = threadIdx.x;
  const int lane = tid & 63, wid = tid >> 6;
  __shared__ u64   pm[64][NOBJ_];
  __shared__ int   sppo[NOBJ_];
  __shared__ float sbox[NOBJ_ * 4];
  __shared__ int   slab[NOBJ_];
  __shared__ float sredA[96], sredB[96];
  __shared__ int   sredI[96];
  __shared__ int   s_npos;
  __shared__ float s_sl1, s_cpos, s_hard;
  __shared__ int   s_last;

  if (tid < 64) sbox[tid] = boxes[img * 64 + tid];
  if (tid < 16) slab[tid] = labels[img * 16 + tid];
  {
    int o = tid & 15, g = tid >> 4;    // g in [0,64)
    u64 m = pob[(size_t)(img * CHUNKS_ + g) * NOBJ_ + o];
    if (g < 32){
      u64 e = pob[(size_t)(img * CHUNKS_ + 64 + g) * NOBJ_ + o];
      if (e > m) m = e;
    }
    pm[g][o] = m;
  }
  if (tid < 96){
    sredI[tid] = npos_c[img * CHUNKS_ + tid];
    sredA[tid] = sl1_c[img * CHUNKS_ + tid];
    sredB[tid] = cpos_c[img * CHUNKS_ + tid];
  }
  __syncthreads();
  if (tid < 16){
    u64 m = pm[0][tid];
    for (int g = 1; g < 64; ++g) if (pm[g][tid] > m) m = pm[g][tid];
    sppo[tid] = (int)(0xFFFFFFFFu - (unsigned)(m & 0xFFFFFFFFull));
  }
  if (tid == 0){
    int c = 0; float s = 0.f, q = 0.f;
    for (int i = 0; i < 96; ++i){ c += sredI[i]; s += sredA[i]; q += sredB[i]; }
    s_npos = c; s_sl1 = s; s_cpos = q;
  }
  __syncthreads();

  // corrections: lanes 0..15 of wave 0 handle the <=16 forced priors
  int npd = 0; float sld = 0.f, cpd = 0.f;
  if (wid == 0 && lane < 16){
    int o = lane, p = sppo[o];
    bool is_last = true;
    for (int o2 = o + 1; o2 < 16; ++o2) if (sppo[o2] == p) is_last = false;
    if (is_last){
      float4 pr = reinterpret_cast<const float4*>(priors)[p];
      float px0 = pr.x - pr.z * 0.5f, py0 = pr.y - pr.w * 0.5f;
      float px1 = pr.x + pr.z * 0.5f, py1 = pr.y + pr.w * 0.5f;
      float pa  = (px1 - px0) * (py1 - py0);
      float mxo = -1.f; int amo = 0;
      for (int oo = 0; oo < 16; ++oo){
        float bx0 = sbox[oo*4+0], by0 = sbox[oo*4+1],
              bx1 = sbox[oo*4+2], by1 = sbox[oo*4+3];
        float ba = (bx1 - bx0) * (by1 - by0);
        float v = iou_pb(bx0, by0, bx1, by1, ba, px0, py0, px1, py1, pa);
        if (v > mxo){ mxo = v; amo = oo; }
      }
      bool pos_old = mxo >= 0.5f;
      size_t row = (size_t)img * P_ + p;
      float4 pl4 = reinterpret_cast<const float4*>(pred_locs)[row];
      float sl_new = sl1_row4(sbox, o, pr, pl4);
      int lab_new = slab[o];
      float s_new = scores[row * (size_t)C_ + lab_new];
      if (pos_old){
        float sl_old = sl1_row4(sbox, amo, pr, pl4);
        float s_old  = scores[row * (size_t)C_ + slab[amo]];
        sld = sl_new - sl_old;
        cpd = s_old - s_new;               // lse cancels
      } else {
        npd = 1;
        float ce0v = ce_neg[row];          // = lse - s0 (>=0 up to rounding)
        float s0   = scores[row * (size_t)C_];
        sld = sl_new;
        cpd = ce0v + s0 - s_new;
        ce_neg[row] = 0.f;                 // now positive: excluded from topk
      }
    }
  }
  if (wid == 0){
    #pragma unroll
    for (int off = 8; off; off >>= 1){
      npd += __shfl_down(npd, off);
      sld += __shfl_down(sld, off);
      cpd += __shfl_down(cpd, off);
    }
    if (lane == 0){
      s_npos += npd; s_sl1 += sld; s_cpos += cpd;
      npos_img[img] = s_npos; sl1_img[img] = s_sl1; cpos_img[img] = s_cpos;
    }
  }
  __threadfence();
  __syncthreads();

  // ---- per-image exact top-K sum (radix select over f32 bits) ----
  const int K = 3 * s_npos;
  const float* v = ce_neg + (size_t)img * P_;
  __shared__ int hist[32 * 257];
  __shared__ int histT[256];
  __shared__ unsigned s_prefix;
  __shared__ int s_rem;
  __shared__ float rsum[16];
  const int copy = tid & 31;

  if (K <= 0){
    if (tid == 0) s_hard = 0.f;
    __syncthreads();
  } else if (K >= P_){
    float s = 0.f;
    for (int p = tid; p < P_; p += 1024) s += v[p];
    #pragma unroll
    for (int off = 32; off; off >>= 1) s += __shfl_down(s, off);
    if (lane == 0) rsum[wid] = s;
    __syncthreads();
    if (tid == 0){
      float t = 0.f;
      for (int w = 0; w < 16; ++w) t += rsum[w];
      s_hard = t;
    }
    __syncthreads();
  } else {
    unsigned prefix = 0; int remaining = K;
    for (int shift = 24; shift >= 0; shift -= 8){
      for (int i = tid; i < 32 * 257; i += 1024) hist[i] = 0;
      __syncthreads();
      unsigned hmask = (shift == 24) ? 0u : (0xFFFFFFFFu << (shift + 8));
      for (int p = tid; p < P_; p += 1024){
        unsigned u = __float_as_uint(v[p]);
        if ((u & hmask) == prefix) atomicAdd(&hist[copy * 257 + ((u >> shift) & 255)], 1);
      }
      __syncthreads();
      if (tid < 256){
        int s = 0;
        #pragma unroll
        for (int w = 0; w < 32; ++w) s += hist[w * 257 + tid];
        histT[tid] = s;
      }
      __syncthreads();
      if (wid == 0){
        int a0 = histT[lane*4+0], a1 = histT[lane*4+1],
            a2 = histT[lane*4+2], a3 = histT[lane*4+3];
        int tl = a0 + a1 + a2 + a3;
        int run = tl;
        #pragma unroll
        for (int off = 1; off < 64; off <<= 1){
          int x = __shfl_down(run, off);
          if (lane + off < 64) run += x;
        }
        int E  = run - tl;
        int s3 = E;
        int s2 = s3 + a3;
        int s1 = s2 + a2;
        int s0 = s1 + a1;
        if (s0 < remaining && s0 + a0 >= remaining){ s_prefix = prefix | ((unsigned)(lane*4+0) << shift); s_rem = remaining - s0; }
        if (s1 < remaining && s1 + a1 >= remaining){ s_prefix = prefix | ((unsigned)(lane*4+1) << shift); s_rem = remaining - s1; }
        if (s2 < remaining && s2 + a2 >= remaining){ s_prefix = prefix | ((unsigned)(lane*4+2) << shift); s_rem = remaining - s2; }
        if (s3 < remaining && s3 + a3 >= remaining){ s_prefix = prefix | ((unsigned)(lane*4+3) << shift); s_rem = remaining - s3; }
      }
      __syncthreads();
      prefix = s_prefix;
      remaining = s_rem;
      __syncthreads();
    }
    float tv = __uint_as_float(prefix);
    float sgt = 0.f;
    for (int p = tid; p < P_; p += 1024){
      unsigned u = __float_as_uint(v[p]);
      if (u > prefix) sgt += v[p];
    }
    #pragma unroll
    for (int off = 32; off; off >>= 1) sgt += __shfl_down(sgt, off);
    if (lane == 0) rsum[wid] = sgt;
    __syncthreads();
    if (tid == 0){
      float s = 0.f;
      for (int w = 0; w < 16; ++w) s += rsum[w];
      s_hard = s + (float)remaining * tv;
    }
    __syncthreads();
  }

  // ---- fused final combine (last block) ----
  if (tid == 0){
    hard_img[img] = s_hard;
    __threadfence();
    int old = atomicAdd(done, 1);
    s_last = (old == B_ - 1) ? 1 : 0;
  }
  __syncthreads();
  if (s_last){
    if (tid == 0) __threadfence();   // acquire: order gather loads after done RMW
    __syncthreads();
    float np = 0.f, sl = 0.f, cp = 0.f, hd = 0.f;
    if (tid < 64){
      np = (float)__hip_atomic_load(&npos_img[tid], __ATOMIC_RELAXED, __HIP_MEMORY_SCOPE_AGENT);
      sl = __hip_atomic_load(&sl1_img[tid],  __ATOMIC_RELAXED, __HIP_MEMORY_SCOPE_AGENT);
      cp = __hip_atomic_load(&cpos_img[tid], __ATOMIC_RELAXED, __HIP_MEMORY_SCOPE_AGENT);
      hd = __hip_atomic_load(&hard_img[tid], __ATOMIC_RELAXED, __HIP_MEMORY_SCOPE_AGENT);
    }
    if (wid == 0){
      #pragma unroll
      for (int off = 32; off; off >>= 1){
        np += __shfl_down(np, off);
        sl += __shfl_down(sl, off);
        cp += __shfl_down(cp, off);
        hd += __shfl_down(hd, off);
      }
      if (lane == 0){
        out[0] = (hd + cp) / np + sl / (np * 4.0f);
      }
    }
  }
}

extern "C" void kernel_launch(void* const* d_in, const int* in_sizes, int n_in,
                              void* d_out, int out_size, void* d_ws, size_t ws_size,
                              hipStream_t stream){
  const float* pred_locs = (const float*)d_in[0];
  const float* scores    = (const float*)d_in[1];
  const float* boxes     = (const float*)d_in[2];
  const int*   labels    = (const int*)d_in[3];
  const float* priors    = (const float*)d_in[4];

  const size_t BP = (size_t)B_ * P_;
  char* w = (char*)d_ws;
  float* ce_neg = (float*)w;                                   // BP f32
  u64*   pob    = (u64*)(w + BP * 4);                          // NBLK_*16 u64
  char*  w2 = w + BP * 4 + (size_t)NBLK_ * NOBJ_ * 8;
  int*   npos_c = (int*)  w2;                                  // NBLK_
  float* sl1_c  = (float*)(w2 + NBLK_ * 4);                    // NBLK_
  float* cpos_c = (float*)(w2 + NBLK_ * 8);                    // NBLK_
  char*  w3 = w2 + NBLK_ * 12;
  int*   npos_img = (int*)  w3;                                // 64
  float* sl1_img  = (float*)(w3 + 256);
  float* cpos_img = (float*)(w3 + 512);
  float* hard_img = (float*)(w3 + 768);
  int*   done     = (int*)  (w3 + 1024);

  dim3 g1(CHUNKS_, B_);
  k_main<<<g1, 64, 0, stream>>>(scores, priors, boxes, labels, pred_locs,
                                ce_neg, pob, npos_c, sl1_c, cpos_c, done);

  k_tail<<<B_, 1024, 0, stream>>>(scores, priors, boxes, labels, pred_locs,
                                  pob, npos_c, sl1_c, cpos_c, ce_neg,
                                  npos_img, sl1_img, cpos_img, hard_img,
                                  done, (float*)d_out);
}